// Round 5
// baseline (1077.924 us; speedup 1.0000x reference)
//
#include <hip/hip_runtime.h>
#include <math.h>

#define NN 100000
#define NE 1600000
#define EPS_BN 1e-5f
#define SCAN_BLK 98  // ceil(NN / 1024)

// ---------------- edge dtype detection (int64 vs int32) ----------------
__global__ void detect_kernel(const int* __restrict__ ei32, int* __restrict__ flag) {
  __shared__ int red[256];
  int t = threadIdx.x;
  int acc = 0;
#pragma unroll
  for (int k = 0; k < 4; ++k) acc |= ei32[2 * (t * 4 + k) + 1];
  red[t] = acc;
  __syncthreads();
  for (int off = 128; off > 0; off >>= 1) {
    if (t < off) red[t] |= red[t + off];
    __syncthreads();
  }
  if (t == 0) *flag = (red[0] == 0) ? 1 : 0;
}

__device__ __forceinline__ int edge_at(const void* ei, long long idx, int is64) {
  if (is64) return (int)((const long long*)ei)[idx];
  return ((const int*)ei)[idx];
}

// ---------------- degree count ----------------
__global__ void deg_kernel(const void* __restrict__ ei, const int* __restrict__ flag,
                           int* __restrict__ cnt) {
  int is64 = *flag;
  for (int e = blockIdx.x * blockDim.x + threadIdx.x; e < NE; e += gridDim.x * blockDim.x) {
    int d = edge_at(ei, (long long)NE + e, is64);
    atomicAdd(&cnt[d], 1);
  }
}

// ---------------- multi-block exclusive scan over cnt[NN] ----------------
__global__ __launch_bounds__(256) void scanA_kernel(const int* __restrict__ cnt,
                                                    int* __restrict__ partial) {
  __shared__ int red[256];
  int t = threadIdx.x;
  int base = blockIdx.x * 256 + t;  // int4 index
  int s = 0;
  if (base * 4 < NN) {
    int4 v = ((const int4*)cnt)[base];
    s = v.x + v.y + v.z + v.w;
  }
  red[t] = s;
  __syncthreads();
  for (int off = 128; off > 0; off >>= 1) {
    if (t < off) red[t] += red[t + off];
    __syncthreads();
  }
  if (t == 0) partial[blockIdx.x] = red[0];
}

__global__ __launch_bounds__(128) void scanB_kernel(const int* __restrict__ partial,
                                                    int* __restrict__ offs,
                                                    int* __restrict__ row_start) {
  __shared__ int sh[128];
  int t = threadIdx.x;
  int v = (t < SCAN_BLK) ? partial[t] : 0;
  sh[t] = v;
  __syncthreads();
  for (int off = 1; off < 128; off <<= 1) {
    int u = (t >= off) ? sh[t - off] : 0;
    __syncthreads();
    sh[t] += u;
    __syncthreads();
  }
  if (t < SCAN_BLK) offs[t] = sh[t] - v;  // exclusive
  if (t == 127) row_start[NN] = sh[127];  // total (== NE)
}

__global__ __launch_bounds__(256) void scanC_kernel(const int* __restrict__ cnt,
                                                    const int* __restrict__ offs,
                                                    int* __restrict__ row_start,
                                                    float* __restrict__ dis) {
  __shared__ int sh[256];
  int t = threadIdx.x;
  int base = blockIdx.x * 256 + t;  // int4 index
  int4 v = make_int4(0, 0, 0, 0);
  bool ok = (base * 4 < NN);
  if (ok) v = ((const int4*)cnt)[base];
  int s = v.x + v.y + v.z + v.w;
  sh[t] = s;
  __syncthreads();
  for (int off = 1; off < 256; off <<= 1) {
    int u = (t >= off) ? sh[t - off] : 0;
    __syncthreads();
    sh[t] += u;
    __syncthreads();
  }
  if (ok) {
    int run = offs[blockIdx.x] + sh[t] - s;
    int i = base * 4;
    row_start[i] = run;
    dis[i] = rsqrtf((float)(v.x + 1));
    run += v.x;
    row_start[i + 1] = run;
    dis[i + 1] = rsqrtf((float)(v.y + 1));
    run += v.y;
    row_start[i + 2] = run;
    dis[i + 2] = rsqrtf((float)(v.z + 1));
    run += v.z;
    row_start[i + 3] = run;
    dis[i + 3] = rsqrtf((float)(v.w + 1));
  }
}

// ---------------- CSR scatter (packed src+weight) ----------------
__global__ void scatter_kernel(const void* __restrict__ ei, const int* __restrict__ flag,
                               const int* __restrict__ row_start, int* __restrict__ cursor,
                               const float* __restrict__ dis, int2* __restrict__ csr_pack) {
  int is64 = *flag;
  for (int e = blockIdx.x * blockDim.x + threadIdx.x; e < NE; e += gridDim.x * blockDim.x) {
    int s = edge_at(ei, e, is64);
    int d = edge_at(ei, (long long)NE + e, is64);
    int pos = row_start[d] + atomicAdd(&cursor[d], 1);
    csr_pack[pos] = make_int2(s, __float_as_int(dis[s]));
  }
}

// ---------------- GEMM: h[N][64] = x[N][K] @ W[64][K]^T ----------------
template <int K>
__global__ __launch_bounds__(256) void gemm_kernel(const float* __restrict__ x,
                                                   const float* __restrict__ Wm,
                                                   float* __restrict__ h) {
  constexpr int KC = K / 4;
  __shared__ float4 ws4[64 * KC];
  __shared__ float4 xs4[64 * KC];
  int t = threadIdx.x;
  int row0 = blockIdx.x * 64;
  const float4* W4 = (const float4*)Wm;
  for (int idx = t; idx < 64 * KC; idx += 256) {
    int j = idx / KC, kc = idx % KC;
    ws4[j * KC + (kc ^ (j & 7))] = W4[idx];
  }
  const float4* x4 = (const float4*)x;
  for (int idx = t; idx < 64 * KC; idx += 256) {
    int r = idx / KC, kc = idx % KC;
    int row = row0 + r;
    float4 v = make_float4(0.f, 0.f, 0.f, 0.f);
    if (row < NN) v = x4[(size_t)row * KC + kc];
    xs4[r * KC + kc] = v;
  }
  __syncthreads();
  int j = t & 63, wv = t >> 6;
  float acc[16];
#pragma unroll
  for (int r = 0; r < 16; ++r) acc[r] = 0.f;
  for (int kc = 0; kc < KC; ++kc) {
    float4 w = ws4[j * KC + (kc ^ (j & 7))];
#pragma unroll
    for (int r = 0; r < 16; ++r) {
      float4 xv = xs4[(wv * 16 + r) * KC + kc];  // wave-uniform -> LDS broadcast
      acc[r] += w.x * xv.x + w.y * xv.y + w.z * xv.z + w.w * xv.w;
    }
  }
#pragma unroll
  for (int r = 0; r < 16; ++r) {
    int row = row0 + wv * 16 + r;
    if (row < NN) h[(size_t)row * 64 + j] = acc[r];
  }
}

// ---------------- CSR aggregation + fused BN stats ----------------
// Lane-group gather: 16 lanes per edge-row, each lane loads float4 (16B)
// -> one wave instruction gathers 4 rows (1KB) for 4x memory-level parallelism.
__global__ __launch_bounds__(256) void agg_kernel(const float4* __restrict__ h4,
                                                  const int* __restrict__ row_start,
                                                  const int2* __restrict__ csr_pack,
                                                  const float* __restrict__ dis,
                                                  float4* __restrict__ agg4,
                                                  float* __restrict__ stats) {
  int t = threadIdx.x, lane = t & 63, wv = t >> 6;
  int c = lane & 15;   // float4 column within row (features 4c..4c+3)
  int g = lane >> 4;   // edge group 0..3
  int gw = blockIdx.x * 4 + wv;
  int nw = gridDim.x * 4;
  float4 ssum = make_float4(0.f, 0.f, 0.f, 0.f);
  float4 ssq = make_float4(0.f, 0.f, 0.f, 0.f);
  for (int i0 = gw; i0 < NN; i0 += nw) {
    int i = __builtin_amdgcn_readfirstlane(i0);  // scalar CSR walk
    int beg = row_start[i], end = row_start[i + 1];
    float di = dis[i];
    // self loop: only group 0 contributes (row i is L1-hot afterwards)
    float4 self = h4[(size_t)i * 16 + c];
    float sw = (g == 0) ? di : 0.f;
    float4 acc = make_float4(self.x * sw, self.y * sw, self.z * sw, self.w * sw);
    for (int e0 = beg; e0 < end; e0 += 4) {
      int e = e0 + g;
      bool ok = (e < end);
      int2 a = csr_pack[ok ? e : beg];
      float w = ok ? __int_as_float(a.y) : 0.f;
      int r = ok ? a.x : i;  // inactive lanes re-read hot self row
      float4 v = h4[(size_t)r * 16 + c];
      acc.x += v.x * w;
      acc.y += v.y * w;
      acc.z += v.z * w;
      acc.w += v.w * w;
    }
    // combine the 4 edge groups: butterfly over lane bits 4,5
#pragma unroll
    for (int m = 16; m <= 32; m <<= 1) {
      acc.x += __shfl_xor(acc.x, m, 64);
      acc.y += __shfl_xor(acc.y, m, 64);
      acc.z += __shfl_xor(acc.z, m, 64);
      acc.w += __shfl_xor(acc.w, m, 64);
    }
    acc.x *= di;
    acc.y *= di;
    acc.z *= di;
    acc.w *= di;
    if (lane < 16) {
      agg4[(size_t)i * 16 + c] = acc;
      ssum.x += acc.x;
      ssum.y += acc.y;
      ssum.z += acc.z;
      ssum.w += acc.w;
      ssq.x += acc.x * acc.x;
      ssq.y += acc.y * acc.y;
      ssq.z += acc.z * acc.z;
      ssq.w += acc.w * acc.w;
    }
  }
  __shared__ float4 redS[4][16];
  __shared__ float4 redQ[4][16];
  if (lane < 16) {
    redS[wv][c] = ssum;
    redQ[wv][c] = ssq;
  }
  __syncthreads();
  if (wv == 0 && lane < 16) {
    float4 a = redS[0][c], q = redQ[0][c];
#pragma unroll
    for (int k = 1; k < 4; ++k) {
      a.x += redS[k][c].x;
      a.y += redS[k][c].y;
      a.z += redS[k][c].z;
      a.w += redS[k][c].w;
      q.x += redQ[k][c].x;
      q.y += redQ[k][c].y;
      q.z += redQ[k][c].z;
      q.w += redQ[k][c].w;
    }
    atomicAdd(&stats[4 * c + 0], a.x);
    atomicAdd(&stats[4 * c + 1], a.y);
    atomicAdd(&stats[4 * c + 2], a.z);
    atomicAdd(&stats[4 * c + 3], a.w);
    atomicAdd(&stats[64 + 4 * c + 0], q.x);
    atomicAdd(&stats[64 + 4 * c + 1], q.y);
    atomicAdd(&stats[64 + 4 * c + 2], q.z);
    atomicAdd(&stats[64 + 4 * c + 3], q.w);
  }
}

// ---------------- fold stats into per-feature scale/shift ----------------
// BN of (agg + b): bias cancels (mean subtraction), so b is never needed.
__global__ void bnp_kernel(const float* __restrict__ stats, const float* __restrict__ g,
                           const float* __restrict__ be, float* __restrict__ bnp) {
  int f = threadIdx.x;
  if (f < 64) {
    float m = stats[f] / (float)NN;
    float v = stats[64 + f] / (float)NN - m * m;
    float sc = g[f] * rsqrtf(fmaxf(v, 0.f) + EPS_BN);
    bnp[f] = sc;
    bnp[64 + f] = be[f] - m * sc;
  }
}

// ---------------- BN apply + ReLU + optional residual ----------------
template <bool RES>
__global__ __launch_bounds__(256) void apply_kernel(const float* __restrict__ agg,
                                                    const float* __restrict__ bnp,
                                                    const float* __restrict__ xres,
                                                    float* __restrict__ out) {
  __shared__ float sc[64], sh[64];
  int t = threadIdx.x;
  if (t < 64) {
    sc[t] = bnp[t];
    sh[t] = bnp[64 + t];
  }
  __syncthreads();
  const int total4 = NN * 16;  // N*64/4
  for (int i = blockIdx.x * blockDim.x + t; i < total4; i += gridDim.x * blockDim.x) {
    float4 a = ((const float4*)agg)[i];
    int f = (i * 4) & 63;
    float4 y;
    y.x = fmaxf(fmaf(a.x, sc[f], sh[f]), 0.f);
    y.y = fmaxf(fmaf(a.y, sc[f + 1], sh[f + 1]), 0.f);
    y.z = fmaxf(fmaf(a.z, sc[f + 2], sh[f + 2]), 0.f);
    y.w = fmaxf(fmaf(a.w, sc[f + 3], sh[f + 3]), 0.f);
    if (RES) {
      float4 xr = ((const float4*)xres)[i];
      y.x += xr.x;
      y.y += xr.y;
      y.z += xr.z;
      y.w += xr.w;
    }
    ((float4*)out)[i] = y;
  }
}

extern "C" void kernel_launch(void* const* d_in, const int* in_sizes, int n_in,
                              void* d_out, int out_size, void* d_ws, size_t ws_size,
                              hipStream_t stream) {
  const float* x0 = (const float*)d_in[0];
  const void* ei = d_in[1];
  const float* W0 = (const float*)d_in[2];
  const float* g0 = (const float*)d_in[4];
  const float* be0 = (const float*)d_in[5];
  const float* W1 = (const float*)d_in[6];
  const float* g1 = (const float*)d_in[8];
  const float* be1 = (const float*)d_in[9];
  const float* W2 = (const float*)d_in[10];
  const float* g2 = (const float*)d_in[12];
  const float* be2 = (const float*)d_in[13];
  float* out = (float*)d_out;

  char* p = (char*)d_ws;
  auto carve = [&](size_t bytes) {
    char* q = p;
    p += (bytes + 255) & ~(size_t)255;
    return (void*)q;
  };
  float* bufA = (float*)carve((size_t)NN * 64 * 4);
  float* bufB = (float*)carve((size_t)NN * 64 * 4);
  float* bufC = (float*)carve((size_t)NN * 64 * 4);
  int* row_start = (int*)carve((size_t)(NN + 1) * 4);
  int* cursor = (int*)carve((size_t)NN * 4);
  float* dis = (float*)carve((size_t)NN * 4);
  int2* csr_pack = (int2*)carve((size_t)NE * 8);
  int* partial = (int*)carve(SCAN_BLK * 4);
  int* offs = (int*)carve(SCAN_BLK * 4);
  float* stats = (float*)carve(128 * 4);
  float* bnp = (float*)carve(128 * 4);
  int* flag = (int*)carve(256);

  // ---- graph preprocessing (once; reused by all 3 layers) ----
  detect_kernel<<<1, 256, 0, stream>>>((const int*)ei, flag);
  hipMemsetAsync(cursor, 0, (size_t)NN * 4, stream);
  deg_kernel<<<2048, 256, 0, stream>>>(ei, flag, cursor);
  scanA_kernel<<<SCAN_BLK, 256, 0, stream>>>(cursor, partial);
  scanB_kernel<<<1, 128, 0, stream>>>(partial, offs, row_start);
  scanC_kernel<<<SCAN_BLK, 256, 0, stream>>>(cursor, offs, row_start, dis);
  hipMemsetAsync(cursor, 0, (size_t)NN * 4, stream);
  scatter_kernel<<<2048, 256, 0, stream>>>(ei, flag, row_start, cursor, dis, csr_pack);

  const int gemm_blocks = (NN + 63) / 64;

  // ---- layer 0 (no residual: 128 -> 64) ----
  hipMemsetAsync(stats, 0, 128 * 4, stream);
  gemm_kernel<128><<<gemm_blocks, 256, 0, stream>>>(x0, W0, bufB);
  agg_kernel<<<2048, 256, 0, stream>>>((const float4*)bufB, row_start, csr_pack, dis,
                                       (float4*)bufC, stats);
  bnp_kernel<<<1, 64, 0, stream>>>(stats, g0, be0, bnp);
  apply_kernel<false><<<1024, 256, 0, stream>>>(bufC, bnp, nullptr, bufA);

  // ---- layer 1 (residual) ----
  hipMemsetAsync(stats, 0, 128 * 4, stream);
  gemm_kernel<64><<<gemm_blocks, 256, 0, stream>>>(bufA, W1, bufB);
  agg_kernel<<<2048, 256, 0, stream>>>((const float4*)bufB, row_start, csr_pack, dis,
                                       (float4*)bufC, stats);
  bnp_kernel<<<1, 64, 0, stream>>>(stats, g1, be1, bnp);
  apply_kernel<true><<<1024, 256, 0, stream>>>(bufC, bnp, bufA, out);

  // ---- layer 2 (residual) ----
  hipMemsetAsync(stats, 0, 128 * 4, stream);
  gemm_kernel<64><<<gemm_blocks, 256, 0, stream>>>(out, W2, bufB);
  agg_kernel<<<2048, 256, 0, stream>>>((const float4*)bufB, row_start, csr_pack, dis,
                                       (float4*)bufC, stats);
  bnp_kernel<<<1, 64, 0, stream>>>(stats, g2, be2, bnp);
  apply_kernel<true><<<1024, 256, 0, stream>>>(bufC, bnp, out, out);
}

// Round 7
// 628.111 us; speedup vs baseline: 1.7161x; 1.7161x over previous
//
#include <hip/hip_runtime.h>
#include <math.h>

#define NN 100000
#define NE 1600000
#define EPS_BN 1e-5f
#define SCAN_BLK 98  // ceil(NN / 1024)

// ---------------- edge dtype detection (int64 vs int32) ----------------
__global__ void detect_kernel(const int* __restrict__ ei32, int* __restrict__ flag) {
  __shared__ int red[256];
  int t = threadIdx.x;
  int acc = 0;
#pragma unroll
  for (int k = 0; k < 4; ++k) acc |= ei32[2 * (t * 4 + k) + 1];
  red[t] = acc;
  __syncthreads();
  for (int off = 128; off > 0; off >>= 1) {
    if (t < off) red[t] |= red[t + off];
    __syncthreads();
  }
  if (t == 0) *flag = (red[0] == 0) ? 1 : 0;
}

__device__ __forceinline__ int edge_at(const void* ei, long long idx, int is64) {
  if (is64) return (int)((const long long*)ei)[idx];
  return ((const int*)ei)[idx];
}

// ---------------- degree count ----------------
__global__ void deg_kernel(const void* __restrict__ ei, const int* __restrict__ flag,
                           int* __restrict__ cnt) {
  int is64 = *flag;
  for (int e = blockIdx.x * blockDim.x + threadIdx.x; e < NE; e += gridDim.x * blockDim.x) {
    int d = edge_at(ei, (long long)NE + e, is64);
    atomicAdd(&cnt[d], 1);
  }
}

// ---------------- multi-block exclusive scan over cnt[NN] ----------------
__global__ __launch_bounds__(256) void scanA_kernel(const int* __restrict__ cnt,
                                                    int* __restrict__ partial) {
  __shared__ int red[256];
  int t = threadIdx.x;
  int base = blockIdx.x * 256 + t;  // int4 index
  int s = 0;
  if (base * 4 < NN) {
    int4 v = ((const int4*)cnt)[base];
    s = v.x + v.y + v.z + v.w;
  }
  red[t] = s;
  __syncthreads();
  for (int off = 128; off > 0; off >>= 1) {
    if (t < off) red[t] += red[t + off];
    __syncthreads();
  }
  if (t == 0) partial[blockIdx.x] = red[0];
}

__global__ __launch_bounds__(128) void scanB_kernel(const int* __restrict__ partial,
                                                    int* __restrict__ offs,
                                                    int* __restrict__ row_start) {
  __shared__ int sh[128];
  int t = threadIdx.x;
  int v = (t < SCAN_BLK) ? partial[t] : 0;
  sh[t] = v;
  __syncthreads();
  for (int off = 1; off < 128; off <<= 1) {
    int u = (t >= off) ? sh[t - off] : 0;
    __syncthreads();
    sh[t] += u;
    __syncthreads();
  }
  if (t < SCAN_BLK) offs[t] = sh[t] - v;  // exclusive
  if (t == 127) row_start[NN] = sh[127];  // total (== NE)
}

__global__ __launch_bounds__(256) void scanC_kernel(const int* __restrict__ cnt,
                                                    const int* __restrict__ offs,
                                                    int* __restrict__ row_start,
                                                    float* __restrict__ dis) {
  __shared__ int sh[256];
  int t = threadIdx.x;
  int base = blockIdx.x * 256 + t;  // int4 index
  int4 v = make_int4(0, 0, 0, 0);
  bool ok = (base * 4 < NN);
  if (ok) v = ((const int4*)cnt)[base];
  int s = v.x + v.y + v.z + v.w;
  sh[t] = s;
  __syncthreads();
  for (int off = 1; off < 256; off <<= 1) {
    int u = (t >= off) ? sh[t - off] : 0;
    __syncthreads();
    sh[t] += u;
    __syncthreads();
  }
  if (ok) {
    int run = offs[blockIdx.x] + sh[t] - s;
    int i = base * 4;
    row_start[i] = run;
    dis[i] = rsqrtf((float)(v.x + 1));
    run += v.x;
    row_start[i + 1] = run;
    dis[i + 1] = rsqrtf((float)(v.y + 1));
    run += v.y;
    row_start[i + 2] = run;
    dis[i + 2] = rsqrtf((float)(v.z + 1));
    run += v.z;
    row_start[i + 3] = run;
    dis[i + 3] = rsqrtf((float)(v.w + 1));
  }
}

// ---------------- CSR scatter (packed src+weight) ----------------
__global__ void scatter_kernel(const void* __restrict__ ei, const int* __restrict__ flag,
                               const int* __restrict__ row_start, int* __restrict__ cursor,
                               const float* __restrict__ dis, int2* __restrict__ csr_pack) {
  int is64 = *flag;
  for (int e = blockIdx.x * blockDim.x + threadIdx.x; e < NE; e += gridDim.x * blockDim.x) {
    int s = edge_at(ei, e, is64);
    int d = edge_at(ei, (long long)NE + e, is64);
    int pos = row_start[d] + atomicAdd(&cursor[d], 1);
    csr_pack[pos] = make_int2(s, __float_as_int(dis[s]));
  }
}

// ---------------- GEMM: h[N][64] = x[N][K] @ W[64][K]^T ----------------
template <int K>
__global__ __launch_bounds__(256) void gemm_kernel(const float* __restrict__ x,
                                                   const float* __restrict__ Wm,
                                                   float* __restrict__ h) {
  constexpr int KC = K / 4;
  __shared__ float4 ws4[64 * KC];
  __shared__ float4 xs4[64 * KC];
  int t = threadIdx.x;
  int row0 = blockIdx.x * 64;
  const float4* W4 = (const float4*)Wm;
  for (int idx = t; idx < 64 * KC; idx += 256) {
    int j = idx / KC, kc = idx % KC;
    ws4[j * KC + (kc ^ (j & 7))] = W4[idx];
  }
  const float4* x4 = (const float4*)x;
  for (int idx = t; idx < 64 * KC; idx += 256) {
    int r = idx / KC, kc = idx % KC;
    int row = row0 + r;
    float4 v = make_float4(0.f, 0.f, 0.f, 0.f);
    if (row < NN) v = x4[(size_t)row * KC + kc];
    xs4[r * KC + kc] = v;
  }
  __syncthreads();
  int j = t & 63, wv = t >> 6;
  float acc[16];
#pragma unroll
  for (int r = 0; r < 16; ++r) acc[r] = 0.f;
  for (int kc = 0; kc < KC; ++kc) {
    float4 w = ws4[j * KC + (kc ^ (j & 7))];
#pragma unroll
    for (int r = 0; r < 16; ++r) {
      float4 xv = xs4[(wv * 16 + r) * KC + kc];  // wave-uniform -> LDS broadcast
      acc[r] += w.x * xv.x + w.y * xv.y + w.z * xv.z + w.w * xv.w;
    }
  }
#pragma unroll
  for (int r = 0; r < 16; ++r) {
    int row = row0 + wv * 16 + r;
    if (row < NN) h[(size_t)row * 64 + j] = acc[r];
  }
}

// ---------------- CSR aggregation + fused BN stats ----------------
// Wave-uniform scalar CSR walk (s_load for edges, SGPR-base gathers), x4 unroll
// -> 4 independent 256B row-gathers in flight per wave.
__global__ __launch_bounds__(256) void agg_kernel(const float* __restrict__ h,
                                                  const int* __restrict__ row_start,
                                                  const int2* __restrict__ csr_pack,
                                                  const float* __restrict__ dis,
                                                  float* __restrict__ agg,
                                                  float* __restrict__ stats) {
  int t = threadIdx.x, lane = t & 63, wv = t >> 6;
  int gw = blockIdx.x * 4 + wv;
  int nw = gridDim.x * 4;
  float ssum = 0.f, ssq = 0.f;
  for (int i0 = gw; i0 < NN; i0 += nw) {
    int i = __builtin_amdgcn_readfirstlane(i0);  // force scalar CSR walk
    int beg = row_start[i], end = row_start[i + 1];
    float di = dis[i];
    float acc = h[(size_t)i * 64 + lane] * di;  // self loop
    int e = beg;
    for (; e + 4 <= end; e += 4) {
      int2 a0 = csr_pack[e];
      int2 a1 = csr_pack[e + 1];
      int2 a2 = csr_pack[e + 2];
      int2 a3 = csr_pack[e + 3];
      float v0 = h[(size_t)a0.x * 64 + lane];
      float v1 = h[(size_t)a1.x * 64 + lane];
      float v2 = h[(size_t)a2.x * 64 + lane];
      float v3 = h[(size_t)a3.x * 64 + lane];
      acc += v0 * __int_as_float(a0.y);
      acc += v1 * __int_as_float(a1.y);
      acc += v2 * __int_as_float(a2.y);
      acc += v3 * __int_as_float(a3.y);
    }
    for (; e < end; ++e) {
      int2 a = csr_pack[e];
      acc += h[(size_t)a.x * 64 + lane] * __int_as_float(a.y);
    }
    acc *= di;
    agg[(size_t)i * 64 + lane] = acc;
    ssum += acc;
    ssq += acc * acc;
  }
  __shared__ float red[2][4][64];
  red[0][wv][lane] = ssum;
  red[1][wv][lane] = ssq;
  __syncthreads();
  if (wv == 0) {
    float a = red[0][0][lane] + red[0][1][lane] + red[0][2][lane] + red[0][3][lane];
    float b = red[1][0][lane] + red[1][1][lane] + red[1][2][lane] + red[1][3][lane];
    atomicAdd(&stats[lane], a);
    atomicAdd(&stats[64 + lane], b);
  }
}

// ---------------- fold stats into per-feature scale/shift ----------------
// BN of (agg + b): bias cancels (mean subtraction), so b is never needed.
__global__ void bnp_kernel(const float* __restrict__ stats, const float* __restrict__ g,
                           const float* __restrict__ be, float* __restrict__ bnp) {
  int f = threadIdx.x;
  if (f < 64) {
    float m = stats[f] / (float)NN;
    float v = stats[64 + f] / (float)NN - m * m;
    float sc = g[f] * rsqrtf(fmaxf(v, 0.f) + EPS_BN);
    bnp[f] = sc;
    bnp[64 + f] = be[f] - m * sc;
  }
}

// ---------------- BN apply + ReLU + optional residual ----------------
template <bool RES>
__global__ __launch_bounds__(256) void apply_kernel(const float* __restrict__ agg,
                                                    const float* __restrict__ bnp,
                                                    const float* __restrict__ xres,
                                                    float* __restrict__ out) {
  __shared__ float sc[64], sh[64];
  int t = threadIdx.x;
  if (t < 64) {
    sc[t] = bnp[t];
    sh[t] = bnp[64 + t];
  }
  __syncthreads();
  const int total4 = NN * 16;  // N*64/4
  for (int i = blockIdx.x * blockDim.x + t; i < total4; i += gridDim.x * blockDim.x) {
    float4 a = ((const float4*)agg)[i];
    int f = (i * 4) & 63;
    float4 y;
    y.x = fmaxf(fmaf(a.x, sc[f], sh[f]), 0.f);
    y.y = fmaxf(fmaf(a.y, sc[f + 1], sh[f + 1]), 0.f);
    y.z = fmaxf(fmaf(a.z, sc[f + 2], sh[f + 2]), 0.f);
    y.w = fmaxf(fmaf(a.w, sc[f + 3], sh[f + 3]), 0.f);
    if (RES) {
      float4 xr = ((const float4*)xres)[i];
      y.x += xr.x;
      y.y += xr.y;
      y.z += xr.z;
      y.w += xr.w;
    }
    ((float4*)out)[i] = y;
  }
}

extern "C" void kernel_launch(void* const* d_in, const int* in_sizes, int n_in,
                              void* d_out, int out_size, void* d_ws, size_t ws_size,
                              hipStream_t stream) {
  const float* x0 = (const float*)d_in[0];
  const void* ei = d_in[1];
  const float* W0 = (const float*)d_in[2];
  const float* g0 = (const float*)d_in[4];
  const float* be0 = (const float*)d_in[5];
  const float* W1 = (const float*)d_in[6];
  const float* g1 = (const float*)d_in[8];
  const float* be1 = (const float*)d_in[9];
  const float* W2 = (const float*)d_in[10];
  const float* g2 = (const float*)d_in[12];
  const float* be2 = (const float*)d_in[13];
  float* out = (float*)d_out;

  char* p = (char*)d_ws;
  auto carve = [&](size_t bytes) {
    char* q = p;
    p += (bytes + 255) & ~(size_t)255;
    return (void*)q;
  };
  float* bufA = (float*)carve((size_t)NN * 64 * 4);
  float* bufB = (float*)carve((size_t)NN * 64 * 4);
  float* bufC = (float*)carve((size_t)NN * 64 * 4);
  int* row_start = (int*)carve((size_t)(NN + 1) * 4);
  int* cursor = (int*)carve((size_t)NN * 4);
  float* dis = (float*)carve((size_t)NN * 4);
  int2* csr_pack = (int2*)carve((size_t)NE * 8);
  int* partial = (int*)carve(SCAN_BLK * 4);
  int* offs = (int*)carve(SCAN_BLK * 4);
  float* stats = (float*)carve(128 * 4);
  float* bnp = (float*)carve(128 * 4);
  int* flag = (int*)carve(256);

  // ---- graph preprocessing (once; reused by all 3 layers) ----
  detect_kernel<<<1, 256, 0, stream>>>((const int*)ei, flag);
  hipMemsetAsync(cursor, 0, (size_t)NN * 4, stream);
  deg_kernel<<<2048, 256, 0, stream>>>(ei, flag, cursor);
  scanA_kernel<<<SCAN_BLK, 256, 0, stream>>>(cursor, partial);
  scanB_kernel<<<1, 128, 0, stream>>>(partial, offs, row_start);
  scanC_kernel<<<SCAN_BLK, 256, 0, stream>>>(cursor, offs, row_start, dis);
  hipMemsetAsync(cursor, 0, (size_t)NN * 4, stream);
  scatter_kernel<<<2048, 256, 0, stream>>>(ei, flag, row_start, cursor, dis, csr_pack);

  const int gemm_blocks = (NN + 63) / 64;

  // ---- layer 0 (no residual: 128 -> 64) ----
  hipMemsetAsync(stats, 0, 128 * 4, stream);
  gemm_kernel<128><<<gemm_blocks, 256, 0, stream>>>(x0, W0, bufB);
  agg_kernel<<<2048, 256, 0, stream>>>(bufB, row_start, csr_pack, dis, bufC, stats);
  bnp_kernel<<<1, 64, 0, stream>>>(stats, g0, be0, bnp);
  apply_kernel<false><<<1024, 256, 0, stream>>>(bufC, bnp, nullptr, bufA);

  // ---- layer 1 (residual) ----
  hipMemsetAsync(stats, 0, 128 * 4, stream);
  gemm_kernel<64><<<gemm_blocks, 256, 0, stream>>>(bufA, W1, bufB);
  agg_kernel<<<2048, 256, 0, stream>>>(bufB, row_start, csr_pack, dis, bufC, stats);
  bnp_kernel<<<1, 64, 0, stream>>>(stats, g1, be1, bnp);
  apply_kernel<true><<<1024, 256, 0, stream>>>(bufC, bnp, bufA, out);

  // ---- layer 2 (residual) ----
  hipMemsetAsync(stats, 0, 128 * 4, stream);
  gemm_kernel<64><<<gemm_blocks, 256, 0, stream>>>(out, W2, bufB);
  agg_kernel<<<2048, 256, 0, stream>>>(bufB, row_start, csr_pack, dis, bufC, stats);
  bnp_kernel<<<1, 64, 0, stream>>>(stats, g2, be2, bnp);
  apply_kernel<true><<<1024, 256, 0, stream>>>(bufC, bnp, out, out);
}

// Round 8
// 571.441 us; speedup vs baseline: 1.8863x; 1.0992x over previous
//
#include <hip/hip_runtime.h>
#include <math.h>

#define NN 100000
#define NE 1600000
#define EPS_BN 1e-5f
#define SCAN_BLK 98  // ceil(NN / 1024)

__device__ __forceinline__ unsigned bf16r(float x) {  // RNE f32->bf16 (as u16)
  unsigned u = __float_as_uint(x);
  return (u + 0x7FFFu + ((u >> 16) & 1u)) >> 16;
}

// ---------------- edge dtype detection (int64 vs int32) ----------------
__global__ void detect_kernel(const int* __restrict__ ei32, int* __restrict__ flag) {
  __shared__ int red[256];
  int t = threadIdx.x;
  int acc = 0;
#pragma unroll
  for (int k = 0; k < 4; ++k) acc |= ei32[2 * (t * 4 + k) + 1];
  red[t] = acc;
  __syncthreads();
  for (int off = 128; off > 0; off >>= 1) {
    if (t < off) red[t] |= red[t + off];
    __syncthreads();
  }
  if (t == 0) *flag = (red[0] == 0) ? 1 : 0;
}

__device__ __forceinline__ int edge_at(const void* ei, long long idx, int is64) {
  if (is64) return (int)((const long long*)ei)[idx];
  return ((const int*)ei)[idx];
}

// ---------------- degree count ----------------
__global__ void deg_kernel(const void* __restrict__ ei, const int* __restrict__ flag,
                           int* __restrict__ cnt) {
  int is64 = *flag;
  for (int e = blockIdx.x * blockDim.x + threadIdx.x; e < NE; e += gridDim.x * blockDim.x) {
    int d = edge_at(ei, (long long)NE + e, is64);
    atomicAdd(&cnt[d], 1);
  }
}

// ---------------- multi-block exclusive scan over cnt[NN] ----------------
__global__ __launch_bounds__(256) void scanA_kernel(const int* __restrict__ cnt,
                                                    int* __restrict__ partial) {
  __shared__ int red[256];
  int t = threadIdx.x;
  int base = blockIdx.x * 256 + t;  // int4 index
  int s = 0;
  if (base * 4 < NN) {
    int4 v = ((const int4*)cnt)[base];
    s = v.x + v.y + v.z + v.w;
  }
  red[t] = s;
  __syncthreads();
  for (int off = 128; off > 0; off >>= 1) {
    if (t < off) red[t] += red[t + off];
    __syncthreads();
  }
  if (t == 0) partial[blockIdx.x] = red[0];
}

__global__ __launch_bounds__(128) void scanB_kernel(const int* __restrict__ partial,
                                                    int* __restrict__ offs,
                                                    int* __restrict__ row_start) {
  __shared__ int sh[128];
  int t = threadIdx.x;
  int v = (t < SCAN_BLK) ? partial[t] : 0;
  sh[t] = v;
  __syncthreads();
  for (int off = 1; off < 128; off <<= 1) {
    int u = (t >= off) ? sh[t - off] : 0;
    __syncthreads();
    sh[t] += u;
    __syncthreads();
  }
  if (t < SCAN_BLK) offs[t] = sh[t] - v;  // exclusive
  if (t == 127) row_start[NN] = sh[127];  // total (== NE)
}

__global__ __launch_bounds__(256) void scanC_kernel(const int* __restrict__ cnt,
                                                    const int* __restrict__ offs,
                                                    int* __restrict__ row_start,
                                                    float* __restrict__ dis) {
  __shared__ int sh[256];
  int t = threadIdx.x;
  int base = blockIdx.x * 256 + t;  // int4 index
  int4 v = make_int4(0, 0, 0, 0);
  bool ok = (base * 4 < NN);
  if (ok) v = ((const int4*)cnt)[base];
  int s = v.x + v.y + v.z + v.w;
  sh[t] = s;
  __syncthreads();
  for (int off = 1; off < 256; off <<= 1) {
    int u = (t >= off) ? sh[t - off] : 0;
    __syncthreads();
    sh[t] += u;
    __syncthreads();
  }
  if (ok) {
    int run = offs[blockIdx.x] + sh[t] - s;
    int i = base * 4;
    row_start[i] = run;
    dis[i] = rsqrtf((float)(v.x + 1));
    run += v.x;
    row_start[i + 1] = run;
    dis[i + 1] = rsqrtf((float)(v.y + 1));
    run += v.y;
    row_start[i + 2] = run;
    dis[i + 2] = rsqrtf((float)(v.z + 1));
    run += v.z;
    row_start[i + 3] = run;
    dis[i + 3] = rsqrtf((float)(v.w + 1));
  }
}

// ---------------- CSR scatter (packed src+weight) ----------------
__global__ void scatter_kernel(const void* __restrict__ ei, const int* __restrict__ flag,
                               const int* __restrict__ row_start, int* __restrict__ cursor,
                               const float* __restrict__ dis, int2* __restrict__ csr_pack) {
  int is64 = *flag;
  for (int e = blockIdx.x * blockDim.x + threadIdx.x; e < NE; e += gridDim.x * blockDim.x) {
    int s = edge_at(ei, e, is64);
    int d = edge_at(ei, (long long)NE + e, is64);
    int pos = row_start[d] + atomicAdd(&cursor[d], 1);
    csr_pack[pos] = make_int2(s, __float_as_int(dis[s]));
  }
}

// ---------------- GEMM: h[N][64] = x[N][K] @ W[64][K]^T, packed bf16 out ----
// h16[row][w] (w=0..31) holds features (2w, 2w+1) as bf16 pair.
template <int K>
__global__ __launch_bounds__(256) void gemm_kernel(const float* __restrict__ x,
                                                   const float* __restrict__ Wm,
                                                   unsigned* __restrict__ h16) {
  constexpr int KC = K / 4;
  __shared__ float4 ws4[64 * KC];
  __shared__ float4 xs4[64 * KC];
  int t = threadIdx.x;
  int row0 = blockIdx.x * 64;
  const float4* W4 = (const float4*)Wm;
  for (int idx = t; idx < 64 * KC; idx += 256) {
    int j = idx / KC, kc = idx % KC;
    ws4[j * KC + (kc ^ (j & 7))] = W4[idx];
  }
  const float4* x4 = (const float4*)x;
  for (int idx = t; idx < 64 * KC; idx += 256) {
    int r = idx / KC, kc = idx % KC;
    int row = row0 + r;
    float4 v = make_float4(0.f, 0.f, 0.f, 0.f);
    if (row < NN) v = x4[(size_t)row * KC + kc];
    xs4[r * KC + kc] = v;
  }
  __syncthreads();
  int j = t & 63, wv = t >> 6;
  float acc[16];
#pragma unroll
  for (int r = 0; r < 16; ++r) acc[r] = 0.f;
  for (int kc = 0; kc < KC; ++kc) {
    float4 w = ws4[j * KC + (kc ^ (j & 7))];
#pragma unroll
    for (int r = 0; r < 16; ++r) {
      float4 xv = xs4[(wv * 16 + r) * KC + kc];  // wave-uniform -> LDS broadcast
      acc[r] += w.x * xv.x + w.y * xv.y + w.z * xv.z + w.w * xv.w;
    }
  }
#pragma unroll
  for (int r = 0; r < 16; ++r) {
    int row = row0 + wv * 16 + r;
    float part = __shfl_xor(acc[r], 1, 64);  // partner feature
    if (row < NN && !(j & 1)) {
      // even lane j: lo = feature j (own), hi = feature j+1 (partner)
      h16[(size_t)row * 32 + (j >> 1)] = bf16r(acc[r]) | (bf16r(part) << 16);
    }
  }
}

// ---------------- CSR aggregation + fused BN stats (bf16 h) ----------------
// Wave-uniform scalar CSR walk; lane l reads word (l&31) of the 128B row and
// extracts feature f = 2*(l&31) + (l>>5). One shfl at the end restores
// lane==feature for stats and the contiguous fp32 store.
__global__ __launch_bounds__(256) void agg_kernel(const unsigned* __restrict__ h16,
                                                  const int* __restrict__ row_start,
                                                  const int2* __restrict__ csr_pack,
                                                  const float* __restrict__ dis,
                                                  float* __restrict__ agg,
                                                  float* __restrict__ stats) {
  int t = threadIdx.x, lane = t & 63, wv = t >> 6;
  int wofs = lane & 31;           // word within row
  bool hi = (lane >= 32);         // which bf16 half this lane owns
  int gw = blockIdx.x * 4 + wv;
  int nw = gridDim.x * 4;
  float ssum = 0.f, ssq = 0.f;
  for (int i0 = gw; i0 < NN; i0 += nw) {
    int i = __builtin_amdgcn_readfirstlane(i0);  // force scalar CSR walk
    int beg = row_start[i], end = row_start[i + 1];
    float di = dis[i];
    unsigned ws = h16[(size_t)i * 32 + wofs];  // self row
    float acc = __uint_as_float(hi ? (ws & 0xFFFF0000u) : (ws << 16)) * di;
    int e = beg;
    for (; e + 4 <= end; e += 4) {
      int2 a0 = csr_pack[e];
      int2 a1 = csr_pack[e + 1];
      int2 a2 = csr_pack[e + 2];
      int2 a3 = csr_pack[e + 3];
      unsigned w0 = h16[(size_t)a0.x * 32 + wofs];
      unsigned w1 = h16[(size_t)a1.x * 32 + wofs];
      unsigned w2 = h16[(size_t)a2.x * 32 + wofs];
      unsigned w3 = h16[(size_t)a3.x * 32 + wofs];
      acc += __uint_as_float(hi ? (w0 & 0xFFFF0000u) : (w0 << 16)) * __int_as_float(a0.y);
      acc += __uint_as_float(hi ? (w1 & 0xFFFF0000u) : (w1 << 16)) * __int_as_float(a1.y);
      acc += __uint_as_float(hi ? (w2 & 0xFFFF0000u) : (w2 << 16)) * __int_as_float(a2.y);
      acc += __uint_as_float(hi ? (w3 & 0xFFFF0000u) : (w3 << 16)) * __int_as_float(a3.y);
    }
    for (; e < end; ++e) {
      int2 a = csr_pack[e];
      unsigned w = h16[(size_t)a.x * 32 + wofs];
      acc += __uint_as_float(hi ? (w & 0xFFFF0000u) : (w << 16)) * __int_as_float(a.y);
    }
    acc *= di;
    // reorder so lane == feature: lane m takes acc from lane (m&1 ? 32+(m>>1) : m>>1)
    int src = ((lane & 1) ? 32 : 0) + (lane >> 1);
    float accF = __shfl(acc, src, 64);
    agg[(size_t)i * 64 + lane] = accF;
    ssum += accF;
    ssq += accF * accF;
  }
  __shared__ float red[2][4][64];
  red[0][wv][lane] = ssum;
  red[1][wv][lane] = ssq;
  __syncthreads();
  if (wv == 0) {
    float a = red[0][0][lane] + red[0][1][lane] + red[0][2][lane] + red[0][3][lane];
    float b = red[1][0][lane] + red[1][1][lane] + red[1][2][lane] + red[1][3][lane];
    atomicAdd(&stats[lane], a);
    atomicAdd(&stats[64 + lane], b);
  }
}

// ---------------- fold stats into per-feature scale/shift ----------------
// BN of (agg + b): bias cancels (mean subtraction), so b is never needed.
__global__ void bnp_kernel(const float* __restrict__ stats, const float* __restrict__ g,
                           const float* __restrict__ be, float* __restrict__ bnp) {
  int f = threadIdx.x;
  if (f < 64) {
    float m = stats[f] / (float)NN;
    float v = stats[64 + f] / (float)NN - m * m;
    float sc = g[f] * rsqrtf(fmaxf(v, 0.f) + EPS_BN);
    bnp[f] = sc;
    bnp[64 + f] = be[f] - m * sc;
  }
}

// ---------------- BN apply + ReLU + optional residual ----------------
template <bool RES>
__global__ __launch_bounds__(256) void apply_kernel(const float* __restrict__ agg,
                                                    const float* __restrict__ bnp,
                                                    const float* __restrict__ xres,
                                                    float* __restrict__ out) {
  __shared__ float sc[64], sh[64];
  int t = threadIdx.x;
  if (t < 64) {
    sc[t] = bnp[t];
    sh[t] = bnp[64 + t];
  }
  __syncthreads();
  const int total4 = NN * 16;  // N*64/4
  for (int i = blockIdx.x * blockDim.x + t; i < total4; i += gridDim.x * blockDim.x) {
    float4 a = ((const float4*)agg)[i];
    int f = (i * 4) & 63;
    float4 y;
    y.x = fmaxf(fmaf(a.x, sc[f], sh[f]), 0.f);
    y.y = fmaxf(fmaf(a.y, sc[f + 1], sh[f + 1]), 0.f);
    y.z = fmaxf(fmaf(a.z, sc[f + 2], sh[f + 2]), 0.f);
    y.w = fmaxf(fmaf(a.w, sc[f + 3], sh[f + 3]), 0.f);
    if (RES) {
      float4 xr = ((const float4*)xres)[i];
      y.x += xr.x;
      y.y += xr.y;
      y.z += xr.z;
      y.w += xr.w;
    }
    ((float4*)out)[i] = y;
  }
}

extern "C" void kernel_launch(void* const* d_in, const int* in_sizes, int n_in,
                              void* d_out, int out_size, void* d_ws, size_t ws_size,
                              hipStream_t stream) {
  const float* x0 = (const float*)d_in[0];
  const void* ei = d_in[1];
  const float* W0 = (const float*)d_in[2];
  const float* g0 = (const float*)d_in[4];
  const float* be0 = (const float*)d_in[5];
  const float* W1 = (const float*)d_in[6];
  const float* g1 = (const float*)d_in[8];
  const float* be1 = (const float*)d_in[9];
  const float* W2 = (const float*)d_in[10];
  const float* g2 = (const float*)d_in[12];
  const float* be2 = (const float*)d_in[13];
  float* out = (float*)d_out;

  char* p = (char*)d_ws;
  auto carve = [&](size_t bytes) {
    char* q = p;
    p += (bytes + 255) & ~(size_t)255;
    return (void*)q;
  };
  float* bufA = (float*)carve((size_t)NN * 64 * 4);
  unsigned* h16 = (unsigned*)carve((size_t)NN * 32 * 4);  // packed bf16 h
  float* bufC = (float*)carve((size_t)NN * 64 * 4);
  int* row_start = (int*)carve((size_t)(NN + 1) * 4);
  int* cursor = (int*)carve((size_t)NN * 4);
  float* dis = (float*)carve((size_t)NN * 4);
  int2* csr_pack = (int2*)carve((size_t)NE * 8);
  int* partial = (int*)carve(SCAN_BLK * 4);
  int* offs = (int*)carve(SCAN_BLK * 4);
  float* stats = (float*)carve(128 * 4);
  float* bnp = (float*)carve(128 * 4);
  int* flag = (int*)carve(256);

  // ---- graph preprocessing (once; reused by all 3 layers) ----
  detect_kernel<<<1, 256, 0, stream>>>((const int*)ei, flag);
  hipMemsetAsync(cursor, 0, (size_t)NN * 4, stream);
  deg_kernel<<<2048, 256, 0, stream>>>(ei, flag, cursor);
  scanA_kernel<<<SCAN_BLK, 256, 0, stream>>>(cursor, partial);
  scanB_kernel<<<1, 128, 0, stream>>>(partial, offs, row_start);
  scanC_kernel<<<SCAN_BLK, 256, 0, stream>>>(cursor, offs, row_start, dis);
  hipMemsetAsync(cursor, 0, (size_t)NN * 4, stream);
  scatter_kernel<<<2048, 256, 0, stream>>>(ei, flag, row_start, cursor, dis, csr_pack);

  const int gemm_blocks = (NN + 63) / 64;

  // ---- layer 0 (no residual: 128 -> 64) ----
  hipMemsetAsync(stats, 0, 128 * 4, stream);
  gemm_kernel<128><<<gemm_blocks, 256, 0, stream>>>(x0, W0, h16);
  agg_kernel<<<2048, 256, 0, stream>>>(h16, row_start, csr_pack, dis, bufC, stats);
  bnp_kernel<<<1, 64, 0, stream>>>(stats, g0, be0, bnp);
  apply_kernel<false><<<1024, 256, 0, stream>>>(bufC, bnp, nullptr, bufA);

  // ---- layer 1 (residual) ----
  hipMemsetAsync(stats, 0, 128 * 4, stream);
  gemm_kernel<64><<<gemm_blocks, 256, 0, stream>>>(bufA, W1, h16);
  agg_kernel<<<2048, 256, 0, stream>>>(h16, row_start, csr_pack, dis, bufC, stats);
  bnp_kernel<<<1, 64, 0, stream>>>(stats, g1, be1, bnp);
  apply_kernel<true><<<1024, 256, 0, stream>>>(bufC, bnp, bufA, out);

  // ---- layer 2 (residual) ----
  hipMemsetAsync(stats, 0, 128 * 4, stream);
  gemm_kernel<64><<<gemm_blocks, 256, 0, stream>>>(out, W2, h16);
  agg_kernel<<<2048, 256, 0, stream>>>(h16, row_start, csr_pack, dis, bufC, stats);
  bnp_kernel<<<1, 64, 0, stream>>>(stats, g2, be2, bnp);
  apply_kernel<true><<<1024, 256, 0, stream>>>(bufC, bnp, out, out);
}

// Round 9
// 553.083 us; speedup vs baseline: 1.9489x; 1.0332x over previous
//
#include <hip/hip_runtime.h>
#include <math.h>

#define NN 100000
#define NE 1600000
#define EPS_BN 1e-5f
#define SCAN_BLK 98  // ceil(NN / 1024)

__device__ __forceinline__ unsigned bf16r(float x) {  // RNE f32->bf16 (as u16)
  unsigned u = __float_as_uint(x);
  return (u + 0x7FFFu + ((u >> 16) & 1u)) >> 16;
}
__device__ __forceinline__ float bf16lo(unsigned w) { return __uint_as_float(w << 16); }
__device__ __forceinline__ float bf16hi(unsigned w) { return __uint_as_float(w & 0xFFFF0000u); }

// ---------------- edge dtype detection (int64 vs int32) ----------------
__global__ void detect_kernel(const int* __restrict__ ei32, int* __restrict__ flag) {
  __shared__ int red[256];
  int t = threadIdx.x;
  int acc = 0;
#pragma unroll
  for (int k = 0; k < 4; ++k) acc |= ei32[2 * (t * 4 + k) + 1];
  red[t] = acc;
  __syncthreads();
  for (int off = 128; off > 0; off >>= 1) {
    if (t < off) red[t] |= red[t + off];
    __syncthreads();
  }
  if (t == 0) *flag = (red[0] == 0) ? 1 : 0;
}

__device__ __forceinline__ int edge_at(const void* ei, long long idx, int is64) {
  if (is64) return (int)((const long long*)ei)[idx];
  return ((const int*)ei)[idx];
}

// ---------------- degree count ----------------
__global__ void deg_kernel(const void* __restrict__ ei, const int* __restrict__ flag,
                           int* __restrict__ cnt) {
  int is64 = *flag;
  for (int e = blockIdx.x * blockDim.x + threadIdx.x; e < NE; e += gridDim.x * blockDim.x) {
    int d = edge_at(ei, (long long)NE + e, is64);
    atomicAdd(&cnt[d], 1);
  }
}

// ---------------- multi-block exclusive scan over cnt[NN] ----------------
__global__ __launch_bounds__(256) void scanA_kernel(const int* __restrict__ cnt,
                                                    int* __restrict__ partial) {
  __shared__ int red[256];
  int t = threadIdx.x;
  int base = blockIdx.x * 256 + t;  // int4 index
  int s = 0;
  if (base * 4 < NN) {
    int4 v = ((const int4*)cnt)[base];
    s = v.x + v.y + v.z + v.w;
  }
  red[t] = s;
  __syncthreads();
  for (int off = 128; off > 0; off >>= 1) {
    if (t < off) red[t] += red[t + off];
    __syncthreads();
  }
  if (t == 0) partial[blockIdx.x] = red[0];
}

__global__ __launch_bounds__(128) void scanB_kernel(const int* __restrict__ partial,
                                                    int* __restrict__ offs,
                                                    int* __restrict__ row_start) {
  __shared__ int sh[128];
  int t = threadIdx.x;
  int v = (t < SCAN_BLK) ? partial[t] : 0;
  sh[t] = v;
  __syncthreads();
  for (int off = 1; off < 128; off <<= 1) {
    int u = (t >= off) ? sh[t - off] : 0;
    __syncthreads();
    sh[t] += u;
    __syncthreads();
  }
  if (t < SCAN_BLK) offs[t] = sh[t] - v;  // exclusive
  if (t == 127) row_start[NN] = sh[127];  // total (== NE)
}

__global__ __launch_bounds__(256) void scanC_kernel(const int* __restrict__ cnt,
                                                    const int* __restrict__ offs,
                                                    int* __restrict__ row_start,
                                                    float* __restrict__ dis) {
  __shared__ int sh[256];
  int t = threadIdx.x;
  int base = blockIdx.x * 256 + t;  // int4 index
  int4 v = make_int4(0, 0, 0, 0);
  bool ok = (base * 4 < NN);
  if (ok) v = ((const int4*)cnt)[base];
  int s = v.x + v.y + v.z + v.w;
  sh[t] = s;
  __syncthreads();
  for (int off = 1; off < 256; off <<= 1) {
    int u = (t >= off) ? sh[t - off] : 0;
    __syncthreads();
    sh[t] += u;
    __syncthreads();
  }
  if (ok) {
    int run = offs[blockIdx.x] + sh[t] - s;
    int i = base * 4;
    row_start[i] = run;
    dis[i] = rsqrtf((float)(v.x + 1));
    run += v.x;
    row_start[i + 1] = run;
    dis[i + 1] = rsqrtf((float)(v.y + 1));
    run += v.y;
    row_start[i + 2] = run;
    dis[i + 2] = rsqrtf((float)(v.z + 1));
    run += v.z;
    row_start[i + 3] = run;
    dis[i + 3] = rsqrtf((float)(v.w + 1));
  }
}

// ---------------- CSR scatter (packed src+weight) ----------------
__global__ void scatter_kernel(const void* __restrict__ ei, const int* __restrict__ flag,
                               const int* __restrict__ row_start, int* __restrict__ cursor,
                               const float* __restrict__ dis, int2* __restrict__ csr_pack) {
  int is64 = *flag;
  for (int e = blockIdx.x * blockDim.x + threadIdx.x; e < NE; e += gridDim.x * blockDim.x) {
    int s = edge_at(ei, e, is64);
    int d = edge_at(ei, (long long)NE + e, is64);
    int pos = row_start[d] + atomicAdd(&cursor[d], 1);
    csr_pack[pos] = make_int2(s, __float_as_int(dis[s]));
  }
}

// ---------------- GEMM: h[N][64] = x[N][K] @ W[64][K]^T, packed bf16 out ----
// h16[row][w] (w=0..31) holds features (2w, 2w+1) as bf16 pair.
template <int K>
__global__ __launch_bounds__(256) void gemm_kernel(const float* __restrict__ x,
                                                   const float* __restrict__ Wm,
                                                   unsigned* __restrict__ h16) {
  constexpr int KC = K / 4;
  __shared__ float4 ws4[64 * KC];
  __shared__ float4 xs4[64 * KC];
  int t = threadIdx.x;
  int row0 = blockIdx.x * 64;
  const float4* W4 = (const float4*)Wm;
  for (int idx = t; idx < 64 * KC; idx += 256) {
    int j = idx / KC, kc = idx % KC;
    ws4[j * KC + (kc ^ (j & 7))] = W4[idx];
  }
  const float4* x4 = (const float4*)x;
  for (int idx = t; idx < 64 * KC; idx += 256) {
    int r = idx / KC, kc = idx % KC;
    int row = row0 + r;
    float4 v = make_float4(0.f, 0.f, 0.f, 0.f);
    if (row < NN) v = x4[(size_t)row * KC + kc];
    xs4[r * KC + kc] = v;
  }
  __syncthreads();
  int j = t & 63, wv = t >> 6;
  float acc[16];
#pragma unroll
  for (int r = 0; r < 16; ++r) acc[r] = 0.f;
  for (int kc = 0; kc < KC; ++kc) {
    float4 w = ws4[j * KC + (kc ^ (j & 7))];
#pragma unroll
    for (int r = 0; r < 16; ++r) {
      float4 xv = xs4[(wv * 16 + r) * KC + kc];  // wave-uniform -> LDS broadcast
      acc[r] += w.x * xv.x + w.y * xv.y + w.z * xv.z + w.w * xv.w;
    }
  }
#pragma unroll
  for (int r = 0; r < 16; ++r) {
    int row = row0 + wv * 16 + r;
    float part = __shfl_xor(acc[r], 1, 64);  // partner feature
    if (row < NN && !(j & 1)) {
      // even lane j: lo = feature j (own), hi = feature j+1 (partner)
      h16[(size_t)row * 32 + (j >> 1)] = bf16r(acc[r]) | (bf16r(part) << 16);
    }
  }
}

// ---------------- CSR aggregation + fused BN stats (bf16 h) ----------------
// Half-wave edge split: lanes 0-31 process edge e, lanes 32-63 edge e+1.
// Edge indices stay SCALAR (s_load); per-lane base = cndmask of two scalars.
// Each gather instruction fetches 2 distinct 128B rows (256B). Each lane
// unpacks both bf16 halves (features 2w, 2w+1). Combine = one shfl_xor(32).
__global__ __launch_bounds__(256) void agg_kernel(const unsigned* __restrict__ h16,
                                                  const int* __restrict__ row_start,
                                                  const int2* __restrict__ csr_pack,
                                                  const float* __restrict__ dis,
                                                  float2* __restrict__ agg2,
                                                  float* __restrict__ stats) {
  int t = threadIdx.x, lane = t & 63, wv = t >> 6;
  int wofs = lane & 31;  // word within 128B row (features 2w, 2w+1)
  int half = lane >> 5;  // which edge of the pair this lane handles
  int gw = blockIdx.x * 4 + wv;
  int nw = gridDim.x * 4;
  float ssumL = 0.f, ssumH = 0.f, ssqL = 0.f, ssqH = 0.f;
  for (int i0 = gw; i0 < NN; i0 += nw) {
    int i = __builtin_amdgcn_readfirstlane(i0);  // scalar CSR walk
    int beg = row_start[i], end = row_start[i + 1];
    float di = dis[i];
    // self loop: half 0 takes it
    unsigned ws = h16[(size_t)i * 32 + wofs];
    float sw = (half == 0) ? di : 0.f;
    float accL = bf16lo(ws) * sw;
    float accH = bf16hi(ws) * sw;
    int e = beg;
#define EDGE_PAIR(eidx)                                            \
  {                                                                \
    int2 a0 = csr_pack[(eidx)];                                    \
    int2 a1 = csr_pack[(eidx) + 1];                                \
    int r = half ? a1.x : a0.x;                                    \
    float wt = __int_as_float(half ? a1.y : a0.y);                 \
    unsigned w = h16[(size_t)r * 32 + wofs];                       \
    accL += bf16lo(w) * wt;                                        \
    accH += bf16hi(w) * wt;                                        \
  }
    for (; e + 8 <= end; e += 8) {
      EDGE_PAIR(e)
      EDGE_PAIR(e + 2)
      EDGE_PAIR(e + 4)
      EDGE_PAIR(e + 6)
    }
    for (; e + 2 <= end; e += 2) {
      EDGE_PAIR(e)
    }
    if (e < end) {  // odd tail: half 1 re-reads hot self row with weight 0
      int2 a = csr_pack[e];
      int r = half ? i : a.x;
      float wt = half ? 0.f : __int_as_float(a.y);
      unsigned w = h16[(size_t)r * 32 + wofs];
      accL += bf16lo(w) * wt;
      accH += bf16hi(w) * wt;
    }
#undef EDGE_PAIR
    // combine the two halves; both end up with the total
    accL += __shfl_xor(accL, 32, 64);
    accH += __shfl_xor(accH, 32, 64);
    accL *= di;
    accH *= di;
    if (lane < 32) {
      agg2[(size_t)i * 32 + wofs] = make_float2(accL, accH);
      ssumL += accL;
      ssumH += accH;
      ssqL += accL * accL;
      ssqH += accH * accH;
    }
  }
  __shared__ float redS[4][64];
  __shared__ float redQ[4][64];
  if (lane < 32) {
    redS[wv][2 * wofs] = ssumL;
    redS[wv][2 * wofs + 1] = ssumH;
    redQ[wv][2 * wofs] = ssqL;
    redQ[wv][2 * wofs + 1] = ssqH;
  }
  __syncthreads();
  if (wv == 0) {
    float a = redS[0][lane] + redS[1][lane] + redS[2][lane] + redS[3][lane];
    float b = redQ[0][lane] + redQ[1][lane] + redQ[2][lane] + redQ[3][lane];
    atomicAdd(&stats[lane], a);
    atomicAdd(&stats[64 + lane], b);
  }
}

// ---------------- fold stats into per-feature scale/shift ----------------
// BN of (agg + b): bias cancels (mean subtraction), so b is never needed.
__global__ void bnp_kernel(const float* __restrict__ stats, const float* __restrict__ g,
                           const float* __restrict__ be, float* __restrict__ bnp) {
  int f = threadIdx.x;
  if (f < 64) {
    float m = stats[f] / (float)NN;
    float v = stats[64 + f] / (float)NN - m * m;
    float sc = g[f] * rsqrtf(fmaxf(v, 0.f) + EPS_BN);
    bnp[f] = sc;
    bnp[64 + f] = be[f] - m * sc;
  }
}

// ---------------- BN apply + ReLU + optional residual ----------------
template <bool RES>
__global__ __launch_bounds__(256) void apply_kernel(const float* __restrict__ agg,
                                                    const float* __restrict__ bnp,
                                                    const float* __restrict__ xres,
                                                    float* __restrict__ out) {
  __shared__ float sc[64], sh[64];
  int t = threadIdx.x;
  if (t < 64) {
    sc[t] = bnp[t];
    sh[t] = bnp[64 + t];
  }
  __syncthreads();
  const int total4 = NN * 16;  // N*64/4
  for (int i = blockIdx.x * blockDim.x + t; i < total4; i += gridDim.x * blockDim.x) {
    float4 a = ((const float4*)agg)[i];
    int f = (i * 4) & 63;
    float4 y;
    y.x = fmaxf(fmaf(a.x, sc[f], sh[f]), 0.f);
    y.y = fmaxf(fmaf(a.y, sc[f + 1], sh[f + 1]), 0.f);
    y.z = fmaxf(fmaf(a.z, sc[f + 2], sh[f + 2]), 0.f);
    y.w = fmaxf(fmaf(a.w, sc[f + 3], sh[f + 3]), 0.f);
    if (RES) {
      float4 xr = ((const float4*)xres)[i];
      y.x += xr.x;
      y.y += xr.y;
      y.z += xr.z;
      y.w += xr.w;
    }
    ((float4*)out)[i] = y;
  }
}

extern "C" void kernel_launch(void* const* d_in, const int* in_sizes, int n_in,
                              void* d_out, int out_size, void* d_ws, size_t ws_size,
                              hipStream_t stream) {
  const float* x0 = (const float*)d_in[0];
  const void* ei = d_in[1];
  const float* W0 = (const float*)d_in[2];
  const float* g0 = (const float*)d_in[4];
  const float* be0 = (const float*)d_in[5];
  const float* W1 = (const float*)d_in[6];
  const float* g1 = (const float*)d_in[8];
  const float* be1 = (const float*)d_in[9];
  const float* W2 = (const float*)d_in[10];
  const float* g2 = (const float*)d_in[12];
  const float* be2 = (const float*)d_in[13];
  float* out = (float*)d_out;

  char* p = (char*)d_ws;
  auto carve = [&](size_t bytes) {
    char* q = p;
    p += (bytes + 255) & ~(size_t)255;
    return (void*)q;
  };
  float* bufA = (float*)carve((size_t)NN * 64 * 4);
  unsigned* h16 = (unsigned*)carve((size_t)NN * 32 * 4);  // packed bf16 h
  float* bufC = (float*)carve((size_t)NN * 64 * 4);
  int* row_start = (int*)carve((size_t)(NN + 1) * 4);
  int* cursor = (int*)carve((size_t)NN * 4);
  float* dis = (float*)carve((size_t)NN * 4);
  int2* csr_pack = (int2*)carve((size_t)NE * 8);
  int* partial = (int*)carve(SCAN_BLK * 4);
  int* offs = (int*)carve(SCAN_BLK * 4);
  float* stats = (float*)carve(128 * 4);
  float* bnp = (float*)carve(128 * 4);
  int* flag = (int*)carve(256);

  // ---- graph preprocessing (once; reused by all 3 layers) ----
  detect_kernel<<<1, 256, 0, stream>>>((const int*)ei, flag);
  hipMemsetAsync(cursor, 0, (size_t)NN * 4, stream);
  deg_kernel<<<2048, 256, 0, stream>>>(ei, flag, cursor);
  scanA_kernel<<<SCAN_BLK, 256, 0, stream>>>(cursor, partial);
  scanB_kernel<<<1, 128, 0, stream>>>(partial, offs, row_start);
  scanC_kernel<<<SCAN_BLK, 256, 0, stream>>>(cursor, offs, row_start, dis);
  hipMemsetAsync(cursor, 0, (size_t)NN * 4, stream);
  scatter_kernel<<<2048, 256, 0, stream>>>(ei, flag, row_start, cursor, dis, csr_pack);

  const int gemm_blocks = (NN + 63) / 64;

  // ---- layer 0 (no residual: 128 -> 64) ----
  hipMemsetAsync(stats, 0, 128 * 4, stream);
  gemm_kernel<128><<<gemm_blocks, 256, 0, stream>>>(x0, W0, h16);
  agg_kernel<<<2048, 256, 0, stream>>>(h16, row_start, csr_pack, dis, (float2*)bufC, stats);
  bnp_kernel<<<1, 64, 0, stream>>>(stats, g0, be0, bnp);
  apply_kernel<false><<<1024, 256, 0, stream>>>(bufC, bnp, nullptr, bufA);

  // ---- layer 1 (residual) ----
  hipMemsetAsync(stats, 0, 128 * 4, stream);
  gemm_kernel<64><<<gemm_blocks, 256, 0, stream>>>(bufA, W1, h16);
  agg_kernel<<<2048, 256, 0, stream>>>(h16, row_start, csr_pack, dis, (float2*)bufC, stats);
  bnp_kernel<<<1, 64, 0, stream>>>(stats, g1, be1, bnp);
  apply_kernel<true><<<1024, 256, 0, stream>>>(bufC, bnp, bufA, out);

  // ---- layer 2 (residual) ----
  hipMemsetAsync(stats, 0, 128 * 4, stream);
  gemm_kernel<64><<<gemm_blocks, 256, 0, stream>>>(out, W2, h16);
  agg_kernel<<<2048, 256, 0, stream>>>(h16, row_start, csr_pack, dis, (float2*)bufC, stats);
  bnp_kernel<<<1, 64, 0, stream>>>(stats, g2, be2, bnp);
  apply_kernel<true><<<1024, 256, 0, stream>>>(bufC, bnp, out, out);
}